// Round 12
// baseline (179.200 us; speedup 1.0000x reference)
//
#include <hip/hip_runtime.h>
#include <hip/hip_fp16.h>

// Problem dims
#define BDIM 32
#define NDIM 400
#define TDIM 315
#define TPAD 320
#define DDIM 512
#define HDIM 256
#define NITER 100

// Workspace layout (bytes) — total 29,495,296 (ws is >=256 MiB per harness fill size)
#define OFS_TAB   0u           // tAb bf16 [320][512] = 327680
#define OFS_TB    327680u      // TB f32 [320][256] = 327680            (end 655360)
#define OFS_WHT   655360u      // WhbT bf16 [256 j][512 k] = 262144     (end 917504)
#define OFS_QPART 917504u      // qpart ull: [2][32][8][320] = 1310720 + stats [32][8][2] = 4096 (end 2232320)
#define QSTATS    163840u      // ull offset of stats atoms within qpart
#define OFS_S1T   2232320u     // s1T bf16 [32][8][320][64] = 10485760  (end 12718080)
#define OFS_FBT   12718080u    // FbT bf16 [32][8][512][64] = 16777216  (end 29495296)

typedef __attribute__((ext_vector_type(8))) short bf16x8;
typedef __attribute__((ext_vector_type(4))) float f32x4;
typedef unsigned long long ull;

// ---------------- bf16 pack/unpack (RNE) ----------------
__device__ __forceinline__ unsigned rne_hi(float x) {
  unsigned u = __float_as_uint(x);
  u += 0x7fffu + ((u >> 16) & 1u);
  return u & 0xffff0000u;
}
__device__ __forceinline__ unsigned pack2(float lo, float hi) {
  return (rne_hi(lo) >> 16) | rne_hi(hi);
}
__device__ __forceinline__ unsigned short bf1(float x) { return (unsigned short)(rne_hi(x) >> 16); }
__device__ __forceinline__ float bfres(float x) {  // x - bf16(x), the lo part
  return x - __uint_as_float(rne_hi(x));
}

// ---------------- DPP wave reduce helpers (VALU pipe, no LDS) ----------------
template <int CTRL, int RMASK>
__device__ __forceinline__ float dppadd(float x) {
  int y = __builtin_amdgcn_update_dpp(0, __float_as_int(x), CTRL, RMASK, 0xf, true);
  return x + __int_as_float(y);
}
template <int CTRL, int RMASK>
__device__ __forceinline__ float dppmax(float x) {
  int y = __builtin_amdgcn_update_dpp(0, __float_as_int(x), CTRL, RMASK, 0xf, true);
  return fmaxf(x, __int_as_float(y));
}

#define LDH 40
#define SBLK 8
#define SROWS 50
#define SRPW 10
#define SLSP 322   // Sls row pitch (floats): n-group bank offset 8 -> 2-way (free)

// ---------------- K0: fused prep ------------------------------------------------------------
// blocks 0..39   : tA = text @ A^T  (bf16x3 split MFMA, hi/lo in-register)
// blocks 40..59  : TB = text @ Wh_bot + bh (same)
// blocks 60..315 : FbT[b][c][d][64n-pad] transpose (one block per (b,c); pad n>=50 zeroed)
// blocks 316..347: WhbT[j][k] transpose of Wh top half
// blocks 348..511: qpart tag zero-fill
__global__ __launch_bounds__(256) void k_prep(const float* __restrict__ F,
                                              const float* __restrict__ Wh,
                                              const float* __restrict__ text,
                                              const float* __restrict__ A,
                                              const float* __restrict__ bh,
                                              unsigned short* __restrict__ tAb,
                                              float* __restrict__ TB,
                                              unsigned short* __restrict__ WhbT,
                                              unsigned short* __restrict__ FbT,
                                              uint4* __restrict__ qzero) {
  __shared__ unsigned short Ahs[64 * LDH], Als[64 * LDH];
  __shared__ unsigned short Bhs[64 * LDH], Bls[64 * LDH];
  __shared__ float Tls[64 * 69];
  const int bid = blockIdx.x, tid = threadIdx.x;
  if (bid >= 60) {
    if (bid < 316) {
      // ---- FbT transpose: block -> (b,c) ----
      const int bb = (bid - 60) >> 3, cc = (bid - 60) & 7;
      const float* Fs = F + ((size_t)bb * NDIM + cc * SROWS) * DDIM;
      unsigned short* Ft = FbT + (size_t)(bb * SBLK + cc) * DDIM * 64;
      for (int d0 = 0; d0 < DDIM; d0 += 64) {
        for (int idx = tid; idx < 800; idx += 256) {
          int nr = idx >> 4, q = idx & 15;
          float4 v = *(const float4*)(Fs + (size_t)nr * DDIM + d0 + q * 4);
          Tls[nr * 69 + q * 4 + 0] = v.x;
          Tls[nr * 69 + q * 4 + 1] = v.y;
          Tls[nr * 69 + q * 4 + 2] = v.z;
          Tls[nr * 69 + q * 4 + 3] = v.w;
        }
        __syncthreads();
#pragma unroll
        for (int p = 0; p < 2; ++p) {
          int idx = p * 256 + tid;
          int dr = idx >> 3, oct = idx & 7;
          unsigned short us[8];
#pragma unroll
          for (int i = 0; i < 8; ++i) {
            int n = oct * 8 + i;
            us[i] = (n < SROWS) ? bf1(Tls[n * 69 + dr]) : (unsigned short)0;
          }
          *(uint4*)(Ft + (size_t)(d0 + dr) * 64 + oct * 8) = *(uint4*)us;
        }
        __syncthreads();
      }
      return;
    }
    if (bid < 348) {
      // ---- WhbT transpose: 32 tiles of [64 k][64 j] ----
      const int ti = bid - 316;
      const int k0 = (ti & 7) * 64, j0 = (ti >> 3) * 64;
      for (int idx = tid; idx < 1024; idx += 256) {
        int kr = idx >> 4, q = idx & 15;
        float4 v = *(const float4*)(Wh + (size_t)(k0 + kr) * HDIM + j0 + q * 4);
        Tls[kr * 69 + q * 4 + 0] = v.x;
        Tls[kr * 69 + q * 4 + 1] = v.y;
        Tls[kr * 69 + q * 4 + 2] = v.z;
        Tls[kr * 69 + q * 4 + 3] = v.w;
      }
      __syncthreads();
#pragma unroll
      for (int p = 0; p < 2; ++p) {
        int idx = p * 256 + tid;
        int jr = idx >> 3, oct = idx & 7;
        unsigned short us[8];
#pragma unroll
        for (int i = 0; i < 8; ++i) us[i] = bf1(Tls[(oct * 8 + i) * 69 + jr]);
        *(uint4*)(WhbT + (size_t)(j0 + jr) * DDIM + k0 + oct * 8) = *(uint4*)us;
      }
      return;
    }
    // ---- qpart zero ----
    const int NQ16 = 82176;  // (1310720 + 4096) / 16
    const int gid = (bid - 348) * 256 + tid;
    const int stride = 164 * 256;
    for (int i = gid; i < NQ16; i += stride) qzero[i] = make_uint4(0u, 0u, 0u, 0u);
    return;
  }
  // ---- GEMM planes (bf16x3 split MFMA) ----
  const int l = tid & 63, wv = tid >> 6;
  const int m = tid >> 2, kq = (tid & 3) * 8;
  f32x4 acc[4] = {};
  if (bid < 40) {
    const int d0 = (bid & 7) * 64, t0 = (bid >> 3) * 64;
    for (int k0 = 0; k0 < 512; k0 += 32) {
      {
        int t = t0 + m;
        float4 v0 = make_float4(0.f, 0.f, 0.f, 0.f), v1 = v0;
        if (t < TDIM) {
          v0 = *(const float4*)(text + (size_t)t * DDIM + k0 + kq);
          v1 = *(const float4*)(text + (size_t)t * DDIM + k0 + kq + 4);
        }
        *(uint4*)(&Ahs[m * LDH + kq]) =
            make_uint4(pack2(v0.x, v0.y), pack2(v0.z, v0.w), pack2(v1.x, v1.y), pack2(v1.z, v1.w));
        *(uint4*)(&Als[m * LDH + kq]) =
            make_uint4(pack2(bfres(v0.x), bfres(v0.y)), pack2(bfres(v0.z), bfres(v0.w)),
                       pack2(bfres(v1.x), bfres(v1.y)), pack2(bfres(v1.z), bfres(v1.w)));
        float4 w0 = *(const float4*)(A + (size_t)(d0 + m) * DDIM + k0 + kq);
        float4 w1 = *(const float4*)(A + (size_t)(d0 + m) * DDIM + k0 + kq + 4);
        *(uint4*)(&Bhs[m * LDH + kq]) =
            make_uint4(pack2(w0.x, w0.y), pack2(w0.z, w0.w), pack2(w1.x, w1.y), pack2(w1.z, w1.w));
        *(uint4*)(&Bls[m * LDH + kq]) =
            make_uint4(pack2(bfres(w0.x), bfres(w0.y)), pack2(bfres(w0.z), bfres(w0.w)),
                       pack2(bfres(w1.x), bfres(w1.y)), pack2(bfres(w1.z), bfres(w1.w)));
      }
      __syncthreads();
      bf16x8 ah = *(const bf16x8*)(&Ahs[(wv * 16 + (l & 15)) * LDH + (l >> 4) * 8]);
      bf16x8 al = *(const bf16x8*)(&Als[(wv * 16 + (l & 15)) * LDH + (l >> 4) * 8]);
#pragma unroll
      for (int c = 0; c < 4; ++c) {
        bf16x8 bh_ = *(const bf16x8*)(&Bhs[(c * 16 + (l & 15)) * LDH + (l >> 4) * 8]);
        bf16x8 bl_ = *(const bf16x8*)(&Bls[(c * 16 + (l & 15)) * LDH + (l >> 4) * 8]);
        acc[c] = __builtin_amdgcn_mfma_f32_16x16x32_bf16(ah, bh_, acc[c], 0, 0, 0);
        acc[c] = __builtin_amdgcn_mfma_f32_16x16x32_bf16(ah, bl_, acc[c], 0, 0, 0);
        acc[c] = __builtin_amdgcn_mfma_f32_16x16x32_bf16(al, bh_, acc[c], 0, 0, 0);
      }
      __syncthreads();
    }
#pragma unroll
    for (int c = 0; c < 4; ++c)
#pragma unroll
      for (int r = 0; r < 4; ++r) {
        int t = t0 + wv * 16 + ((l >> 4) << 2) + r;  // pad rows (>=315) are exact zeros
        int d = d0 + c * 16 + (l & 15);
        tAb[(size_t)t * DDIM + d] = bf1(acc[c][r]);
      }
  } else {
    const int idx = bid - 40;
    const int h0 = (idx & 3) * 64, t0 = (idx >> 2) * 64;
    const float* Wb = Wh + DDIM * HDIM;  // bottom half, [k][h]
    const int col = tid & 31, g = tid >> 5;
    for (int k0 = 0; k0 < 512; k0 += 32) {
      {
        int t = t0 + m;
        float4 v0 = make_float4(0.f, 0.f, 0.f, 0.f), v1 = v0;
        if (t < TDIM) {
          v0 = *(const float4*)(text + (size_t)t * DDIM + k0 + kq);
          v1 = *(const float4*)(text + (size_t)t * DDIM + k0 + kq + 4);
        }
        *(uint4*)(&Ahs[m * LDH + kq]) =
            make_uint4(pack2(v0.x, v0.y), pack2(v0.z, v0.w), pack2(v1.x, v1.y), pack2(v1.z, v1.w));
        *(uint4*)(&Als[m * LDH + kq]) =
            make_uint4(pack2(bfres(v0.x), bfres(v0.y)), pack2(bfres(v0.z), bfres(v0.w)),
                       pack2(bfres(v1.x), bfres(v1.y)), pack2(bfres(v1.z), bfres(v1.w)));
        float4 w0 = *(const float4*)(Wb + (size_t)(k0 + col) * HDIM + h0 + g * 8);
        float4 w1 = *(const float4*)(Wb + (size_t)(k0 + col) * HDIM + h0 + g * 8 + 4);
        float wr[8] = {w0.x, w0.y, w0.z, w0.w, w1.x, w1.y, w1.z, w1.w};
#pragma unroll
        for (int i = 0; i < 8; ++i) {
          Bhs[(g * 8 + i) * LDH + col] = bf1(wr[i]);
          Bls[(g * 8 + i) * LDH + col] = bf1(bfres(wr[i]));
        }
      }
      __syncthreads();
      bf16x8 ah = *(const bf16x8*)(&Ahs[(wv * 16 + (l & 15)) * LDH + (l >> 4) * 8]);
      bf16x8 al = *(const bf16x8*)(&Als[(wv * 16 + (l & 15)) * LDH + (l >> 4) * 8]);
#pragma unroll
      for (int c = 0; c < 4; ++c) {
        bf16x8 bh_ = *(const bf16x8*)(&Bhs[(c * 16 + (l & 15)) * LDH + (l >> 4) * 8]);
        bf16x8 bl_ = *(const bf16x8*)(&Bls[(c * 16 + (l & 15)) * LDH + (l >> 4) * 8]);
        acc[c] = __builtin_amdgcn_mfma_f32_16x16x32_bf16(ah, bh_, acc[c], 0, 0, 0);
        acc[c] = __builtin_amdgcn_mfma_f32_16x16x32_bf16(ah, bl_, acc[c], 0, 0, 0);
        acc[c] = __builtin_amdgcn_mfma_f32_16x16x32_bf16(al, bh_, acc[c], 0, 0, 0);
      }
      __syncthreads();
    }
#pragma unroll
    for (int c = 0; c < 4; ++c)
#pragma unroll
      for (int r = 0; r < 4; ++r) {
        int t = t0 + wv * 16 + ((l >> 4) << 2) + r;
        int h = h0 + c * 16 + (l & 15);
        TB[(size_t)t * HDIM + h] = acc[c][r] + bh[h];
      }
  }
}

// ---------------- K3: fused s-GEMM + instnorm + sinkhorn (s1T output) -----------------------
// Deltas vs R9 (all bit-identical math): Sls pitch 322 (S-write 4-way -> 2-way free);
// epilogue transpose as u32 pairs into [320][37] u32 (8-way -> 2-way, half the stores);
// publish parallelized across 5 waves (wave wv owns t-slice wv, same summation order).
__global__ __launch_bounds__(320, 1) void k_sinkhorn(const float* __restrict__ F,
                                                     const unsigned short* __restrict__ tAb,
                                                     const float* __restrict__ gptr,
                                                     const float* __restrict__ bptr,
                                                     unsigned short* __restrict__ s1T,
                                                     ull* __restrict__ qpart) {
  __shared__ unsigned short Fch[64 * LDH];    // F rows chunk   [64][32]
  __shared__ unsigned short tACh[320 * LDH];  // tA rows chunk  [320][32]
  __shared__ float Sls[SROWS * SLSP];         // S-tile fp32 (reused as u32 [320][37] later)
  __shared__ float qpl[5][320];               // per-wave own col partials
  __shared__ float qg[5][320];                // per-wave gathered cc-slice sums
  __shared__ float sred[16];
  const int b = blockIdx.x, c = blockIdx.y;
  const int tid = threadIdx.x, wv = tid >> 6, l = tid & 63;
  const float* Fs = F + ((size_t)b * NDIM + (size_t)c * SROWS) * DDIM;
  const float TOL = 1e-3f;
  const float TN_RATIO = 315.0f / 400.0f;

  // ---- phase 1: S-tile MFMA (F fp32 -> bf16 in-register, same bits as pre-packed path) ----
  f32x4 acc[16] = {};  // [tt][nt]
  {
    const int m = tid >> 2, kq = (tid & 3) * 8;
    for (int k0 = 0; k0 < 512; k0 += 32) {
      if (m < 64) {
        uint4 fv = make_uint4(0, 0, 0, 0);
        if (m < SROWS) {
          float4 v0 = *(const float4*)(Fs + (size_t)m * DDIM + k0 + kq);
          float4 v1 = *(const float4*)(Fs + (size_t)m * DDIM + k0 + kq + 4);
          fv = make_uint4(pack2(v0.x, v0.y), pack2(v0.z, v0.w),
                          pack2(v1.x, v1.y), pack2(v1.z, v1.w));
        }
        *(uint4*)(&Fch[m * LDH + kq]) = fv;
      }
#pragma unroll
      for (int p = 0; p < 4; ++p) {
        int row = p * 80 + m;
        *(uint4*)(&tACh[row * LDH + kq]) = *(const uint4*)(tAb + (size_t)row * DDIM + k0 + kq);
      }
      __syncthreads();
      bf16x8 af[4];
#pragma unroll
      for (int nt = 0; nt < 4; ++nt)
        af[nt] = *(const bf16x8*)(&Fch[(nt * 16 + (l & 15)) * LDH + (l >> 4) * 8]);
#pragma unroll
      for (int tt = 0; tt < 4; ++tt) {
        bf16x8 bf_ = *(const bf16x8*)(&tACh[((wv * 4 + tt) * 16 + (l & 15)) * LDH + (l >> 4) * 8]);
#pragma unroll
        for (int nt = 0; nt < 4; ++nt)
          acc[tt * 4 + nt] = __builtin_amdgcn_mfma_f32_16x16x32_bf16(af[nt], bf_, acc[tt * 4 + nt], 0, 0, 0);
      }
      __syncthreads();
    }
  }
  // ---- write S-tile to LDS + local stats partial ----
  float ls = 0.f, lq = 0.f;
#pragma unroll
  for (int tt = 0; tt < 4; ++tt) {
    int t = (wv * 4 + tt) * 16 + (l & 15);
    bool tv = (t < TDIM);
#pragma unroll
    for (int nt = 0; nt < 4; ++nt)
#pragma unroll
      for (int r = 0; r < 4; ++r) {
        int n = nt * 16 + ((l >> 4) << 2) + r;
        if (n < SROWS && tv) {
          float v = acc[tt * 4 + nt][r];
          Sls[n * SLSP + t] = v;
          ls += v;
          lq = fmaf(v, v, lq);
        }
      }
  }
#pragma unroll
  for (int mm = 1; mm <= 32; mm <<= 1) {
    ls += __shfl_xor(ls, mm, 64);
    lq += __shfl_xor(lq, mm, 64);
  }
  if (l == 0) { sred[wv] = ls; sred[8 + wv] = lq; }
  __syncthreads();
  // ---- stats exchange ----
  {
    ull* satoms = qpart + QSTATS;
    if (tid == 0) {
      float Ssum = sred[0] + sred[1] + sred[2] + sred[3] + sred[4];
      float Sq = sred[8] + sred[9] + sred[10] + sred[11] + sred[12];
      ull* mine = satoms + ((size_t)b * SBLK + c) * 2;
      __hip_atomic_store(&mine[0], (1ull << 32) | (ull)__float_as_uint(Ssum),
                         __ATOMIC_RELAXED, __HIP_MEMORY_SCOPE_AGENT);
      __hip_atomic_store(&mine[1], (1ull << 32) | (ull)__float_as_uint(Sq),
                         __ATOMIC_RELAXED, __HIP_MEMORY_SCOPE_AGENT);
    }
    if (wv == 0) {
      ull g = (1ull << 32);
      const ull* base = satoms + (size_t)b * SBLK * 2;
      if (l < 16) g = __hip_atomic_load(&base[l], __ATOMIC_RELAXED, __HIP_MEMORY_SCOPE_AGENT);
      int guard = 0;
      for (;;) {
        if (__ballot((unsigned)(g >> 32) >= 1u) == ~0ull) break;
        if (++guard > (1 << 20)) break;  // deadlock escape (should never trigger)
        if (l < 16 && (unsigned)(g >> 32) < 1u)
          g = __hip_atomic_load(&base[l], __ATOMIC_RELAXED, __HIP_MEMORY_SCOPE_AGENT);
      }
      if (l < 16) sred[l] = __uint_as_float((unsigned)g);
    }
  }
  __syncthreads();
  const float NT = 400.0f * 315.0f;
  const float Ssum_all = ((sred[0] + sred[2]) + (sred[4] + sred[6])) +
                         ((sred[8] + sred[10]) + (sred[12] + sred[14]));
  const float Sq_all = ((sred[1] + sred[3]) + (sred[5] + sred[7])) +
                       ((sred[9] + sred[11]) + (sred[13] + sred[15]));
  const float mean = Ssum_all / NT;
  const float var = Sq_all / NT - mean * mean;
  const float inv = rsqrtf(var + 1e-5f);
  const float alpha = gptr[0] * inv;
  const float L2E = 1.4426950408889634f;
  const float a2 = alpha * L2E;
  const float d2 = (bptr[0] - mean * alpha) * L2E;

  // ---- E = exp(instnorm(S)) from fp32 LDS ----
  float E0[SRPW], E1[SRPW], E2[SRPW], E3[SRPW], E4[SRPW];
#pragma unroll
  for (int j = 0; j < SRPW; ++j) {
    const float* row = Sls + (wv * SRPW + j) * SLSP;
    E0[j] = __builtin_amdgcn_exp2f(fmaf(row[l], a2, d2));
    E1[j] = __builtin_amdgcn_exp2f(fmaf(row[64 + l], a2, d2));
    E2[j] = __builtin_amdgcn_exp2f(fmaf(row[128 + l], a2, d2));
    E3[j] = __builtin_amdgcn_exp2f(fmaf(row[192 + l], a2, d2));
    E4[j] = (l < 59) ? __builtin_amdgcn_exp2f(fmaf(row[256 + l], a2, d2)) : 0.0f;
  }
  float w0 = 1.0f, w1 = 1.0f, w2 = 1.0f, w3 = 1.0f, w4 = (l < 59) ? 1.0f : 0.0f;
  float aj[SRPW];
#pragma unroll
  for (int j = 0; j < SRPW; ++j) aj[j] = 0.0f;

  bool fin = false;
  for (int it = 0; it < NITER; ++it) {
    float p[SRPW];
#pragma unroll
    for (int j = 0; j < SRPW; ++j) {
      float t = E4[j] * w4;
      t = fmaf(E3[j], w3, t);
      t = fmaf(E2[j], w2, t);
      t = fmaf(E1[j], w1, t);
      p[j] = fmaf(E0[j], w0, t);
    }
#pragma unroll
    for (int j = 0; j < SRPW; ++j) p[j] = dppadd<0x111, 0xf>(p[j]);
#pragma unroll
    for (int j = 0; j < SRPW; ++j) p[j] = dppadd<0x112, 0xf>(p[j]);
#pragma unroll
    for (int j = 0; j < SRPW; ++j) p[j] = dppadd<0x114, 0xf>(p[j]);
#pragma unroll
    for (int j = 0; j < SRPW; ++j) p[j] = dppadd<0x118, 0xf>(p[j]);
#pragma unroll
    for (int j = 0; j < SRPW; ++j) p[j] = dppadd<0x142, 0xa>(p[j]);
#pragma unroll
    for (int j = 0; j < SRPW; ++j) p[j] = dppadd<0x143, 0xc>(p[j]);
#pragma unroll
    for (int j = 0; j < SRPW; ++j) {
      float r = __builtin_amdgcn_rcpf(p[j]);
      aj[j] = __int_as_float(__builtin_amdgcn_readlane(__float_as_int(r), 63));
    }
    float q0 = 0.f, q1 = 0.f, q2 = 0.f, q3 = 0.f, q4 = 0.f;
#pragma unroll
    for (int j = 0; j < SRPW; ++j) {
      q0 = fmaf(E0[j], aj[j], q0);
      q1 = fmaf(E1[j], aj[j], q1);
      q2 = fmaf(E2[j], aj[j], q2);
      q3 = fmaf(E3[j], aj[j], q3);
      q4 = fmaf(E4[j], aj[j], q4);
    }
    qpl[wv][l] = q0;
    qpl[wv][64 + l] = q1;
    qpl[wv][128 + l] = q2;
    qpl[wv][192 + l] = q3;
    qpl[wv][256 + l] = q4;
    __syncthreads();
    const int par = it & 1;
    const unsigned tgt = (unsigned)(it + 1);
    ull* bufpar = qpart + ((size_t)par * BDIM + b) * (SBLK * 320);
    // ---- publish own partial, parallel across waves: wave wv owns t-slice wv ----
    {
      ull* myp = bufpar + c * 320;
      const int t = wv * 64 + l;
      float sm = qpl[0][t] + qpl[1][t] + qpl[2][t] + qpl[3][t] + qpl[4][t];
      __hip_atomic_store(&myp[t], ((ull)tgt << 32) | (ull)__float_as_uint(sm),
                         __ATOMIC_RELAXED, __HIP_MEMORY_SCOPE_AGENT);
    }
    // ---- gather: wave wv covers cc = wv and (wv+5 if wv<3); own cc from LDS ----
    {
      const int ncc = (wv < 3) ? 2 : 1;
      ull got[2][5];
      const int ccs[2] = {wv, wv + 5};
#pragma unroll
      for (int e = 0; e < 2; ++e)
        if (e < ncc && ccs[e] != c) {
#pragma unroll
          for (int k = 0; k < 5; ++k)
            got[e][k] = __hip_atomic_load(&bufpar[ccs[e] * 320 + k * 64 + l],
                                          __ATOMIC_RELAXED, __HIP_MEMORY_SCOPE_AGENT);
        }
      int guard = 0;
      for (;;) {
        bool ok = true;
#pragma unroll
        for (int e = 0; e < 2; ++e)
          if (e < ncc && ccs[e] != c) {
#pragma unroll
            for (int k = 0; k < 5; ++k)
              if ((unsigned)(got[e][k] >> 32) != tgt) {
                got[e][k] = __hip_atomic_load(&bufpar[ccs[e] * 320 + k * 64 + l],
                                              __ATOMIC_RELAXED, __HIP_MEMORY_SCOPE_AGENT);
                ok = false;
              }
          }
        if (ok) break;
        if (++guard > (1 << 20)) break;  // deadlock escape (should never trigger)
      }
      float part[5] = {0.f, 0.f, 0.f, 0.f, 0.f};
#pragma unroll
      for (int e = 0; e < 2; ++e)
        if (e < ncc) {
#pragma unroll
          for (int k = 0; k < 5; ++k) {
            int t = k * 64 + l;
            float v = (ccs[e] == c)
                          ? (qpl[0][t] + qpl[1][t] + qpl[2][t] + qpl[3][t] + qpl[4][t])
                          : __uint_as_float((unsigned)got[e][k]);
            part[k] += v;
          }
        }
#pragma unroll
      for (int k = 0; k < 5; ++k) qg[wv][k * 64 + l] = part[k];
    }
    __syncthreads();
    const float Q0 = qg[0][l] + qg[1][l] + qg[2][l] + qg[3][l] + qg[4][l];
    const float Q1 = qg[0][64 + l] + qg[1][64 + l] + qg[2][64 + l] + qg[3][64 + l] + qg[4][64 + l];
    const float Q2 =
        qg[0][128 + l] + qg[1][128 + l] + qg[2][128 + l] + qg[3][128 + l] + qg[4][128 + l];
    const float Q3 =
        qg[0][192 + l] + qg[1][192 + l] + qg[2][192 + l] + qg[3][192 + l] + qg[4][192 + l];
    const float Q4 =
        qg[0][256 + l] + qg[1][256 + l] + qg[2][256 + l] + qg[3][256 + l] + qg[4][256 + l];
    float r = fabsf(fmaf(Q0 * w0, TN_RATIO, -1.0f));
    r = fmaxf(r, fabsf(fmaf(Q1 * w1, TN_RATIO, -1.0f)));
    r = fmaxf(r, fabsf(fmaf(Q2 * w2, TN_RATIO, -1.0f)));
    r = fmaxf(r, fabsf(fmaf(Q3 * w3, TN_RATIO, -1.0f)));
    if (l < 59) r = fmaxf(r, fabsf(fmaf(Q4 * w4, TN_RATIO, -1.0f)));
    w0 = __builtin_amdgcn_rcpf(Q0);
    w1 = __builtin_amdgcn_rcpf(Q1);
    w2 = __builtin_amdgcn_rcpf(Q2);
    w3 = __builtin_amdgcn_rcpf(Q3);
    if (l < 59) w4 = __builtin_amdgcn_rcpf(Q4);
    if (fin) break;
    r = dppmax<0x111, 0xf>(r);
    r = dppmax<0x112, 0xf>(r);
    r = dppmax<0x114, 0xf>(r);
    r = dppmax<0x118, 0xf>(r);
    r = dppmax<0x142, 0xa>(r);
    r = dppmax<0x143, 0xc>(r);
    const float resid = __int_as_float(__builtin_amdgcn_readlane(__float_as_int(r), 63));
    fin = (resid < TOL) || (it == NITER - 2);
  }

  // ---- epilogue: s1 -> LDS u32-pair transpose [320 t][37 u32] -> s1T coalesced ----
  {
    unsigned* SlsT32 = (unsigned*)Sls;
    // zero the n-pad words (u32 idx 25..31 == n 50..63) for all 320 t rows
    for (int i = tid; i < 320 * 7; i += 320) {
      int t = i / 7, w = 25 + (i % 7);
      SlsT32[t * 37 + w] = 0u;
    }
#pragma unroll
    for (int jj = 0; jj < SRPW; jj += 2) {
      const int w = wv * 5 + (jj >> 1);  // u32 index; n = 2w (low), 2w+1 (high)
      const float a0 = aj[jj], a1 = aj[jj + 1];
      SlsT32[(size_t)l * 37 + w] = pack2(a0 * E0[jj] * w0, a1 * E0[jj + 1] * w0);
      SlsT32[(size_t)(64 + l) * 37 + w] = pack2(a0 * E1[jj] * w1, a1 * E1[jj + 1] * w1);
      SlsT32[(size_t)(128 + l) * 37 + w] = pack2(a0 * E2[jj] * w2, a1 * E2[jj + 1] * w2);
      SlsT32[(size_t)(192 + l) * 37 + w] = pack2(a0 * E3[jj] * w3, a1 * E3[jj + 1] * w3);
      SlsT32[(size_t)(256 + l) * 37 + w] =
          (l < 59) ? pack2(a0 * E4[jj] * w4, a1 * E4[jj + 1] * w4) : 0u;
    }
    __syncthreads();
    unsigned* S1c32 = (unsigned*)(s1T + (size_t)(b * SBLK + c) * 320 * 64);
    for (int i = tid; i < 320 * 32; i += 320) {
      int row = i >> 5, w = i & 31;
      S1c32[(size_t)row * 32 + w] = SlsT32[row * 37 + w];
    }
  }
}

// ---------------- K4: fused f1 + h + pred ---------------------------------------------------
// Grid (32 b, 5 tt). Phase 1: f1_tile[64 t][512 d] = sum_c s1T[c][t][:].FbT[c][d][:]
// (K=512 padded n; pads are exact zeros). All staging natural-row uint4. f1 tile held in
// LDS bf16 (identical rounding to the old f1b buffer). Phase 2: h=relu(f1@WhbT^T + TB),
// pred = h@Wo + bo, direct store. Batch-major grid -> per-batch set XCD/L2-resident.
__global__ __launch_bounds__(256) void k_out(const unsigned short* __restrict__ s1T,
                                             const unsigned short* __restrict__ FbT,
                                             const unsigned short* __restrict__ WhbT,
                                             const float* __restrict__ TB,
                                             const float* __restrict__ Wo,
                                             const float* __restrict__ bo,
                                             float* __restrict__ out) {
  __shared__ unsigned short Abf[64 * LDH];   // 5 KB
  __shared__ unsigned short Bbf[512 * LDH];  // 40 KB (reused in phase 2 for WhbT)
  __shared__ unsigned short f1L[64 * 520];   // 66.6 KB
  __shared__ float Wos[256];
  __shared__ float predp[4][64];
  const int b = blockIdx.x, t0 = blockIdx.y * 64;
  const int tid = threadIdx.x, l = tid & 63, wv = tid >> 6;
  Wos[tid] = Wo[tid];
  const unsigned short* S1b = s1T + (size_t)b * SBLK * 320 * 64;
  const unsigned short* Fbt = FbT + (size_t)b * SBLK * DDIM * 64;
  const int m = tid >> 2, kq = (tid & 3) * 8;
  // ---- phase 1 ----
  f32x4 acc[32] = {};  // [tt][dt] : wave owns 64 t x 128 d
  for (int ch = 0; ch < 16; ++ch) {
    const int c = ch >> 1, h = ch & 1;
    *(uint4*)(&Abf[m * LDH + kq]) =
        *(const uint4*)(S1b + ((size_t)c * 320 + t0 + m) * 64 + h * 32 + kq);
#pragma unroll
    for (int p = 0; p < 8; ++p) {
      int idx = p * 256 + tid;
      int d = idx >> 2, q = idx & 3;
      *(uint4*)(&Bbf[d * LDH + q * 8]) =
          *(const uint4*)(Fbt + ((size_t)c * DDIM + d) * 64 + h * 32 + q * 8);
    }
    __syncthreads();
    bf16x8 af[4];
#pragma unroll
    for (int tt = 0; tt < 4; ++tt)
      af[tt] = *(const bf16x8*)(&Abf[(tt * 16 + (l & 15)) * LDH + (l >> 4) * 8]);
#pragma unroll
    for (int dt = 0; dt < 8; ++dt) {
      bf16x8 bf_ = *(const bf16x8*)(&Bbf[(wv * 128 + dt * 16 + (l & 15)) * LDH + (l >> 4) * 8]);
#pragma unroll
      for (int tt = 0; tt < 4; ++tt)
        acc[tt * 8 + dt] =
            __builtin_amdgcn_mfma_f32_16x16x32_bf16(af[tt], bf_, acc[tt * 8 + dt], 0, 0, 0);
    }
    __syncthreads();
  }
  // ---- f1 tile -> LDS bf16 ----
#pragma unroll
  for (int tt = 0; tt < 4; ++tt)
#pragma unroll
    for (int dt = 0; dt < 8; ++dt)
#pragma unroll
      for (int r = 0; r < 4; ++r) {
        int t_loc = tt * 16 + ((l >> 4) << 2) + r;
        int d = wv * 128 + dt * 16 + (l & 15);
        f1L[t_loc * 520 + d] = bf1(acc[tt * 8 + dt][r]);
      }
  __syncthreads();
  // ---- phase 2 ----
  f32x4 acc2[16] = {};  // [rt][jt] : wave owns 64 r x 64 j
  for (int k0 = 0; k0 < 512; k0 += 32) {
#pragma unroll
    for (int p = 0; p < 4; ++p) {
      int idx = p * 256 + tid;
      int j = idx >> 2, q = idx & 3;
      *(uint4*)(&Bbf[j * LDH + q * 8]) = *(const uint4*)(WhbT + (size_t)j * DDIM + k0 + q * 8);
    }
    __syncthreads();
    bf16x8 af2[4];
#pragma unroll
    for (int rt = 0; rt < 4; ++rt)
      af2[rt] = *(const bf16x8*)(&f1L[(rt * 16 + (l & 15)) * 520 + (l >> 4) * 8 + k0]);
#pragma unroll
    for (int jt = 0; jt < 4; ++jt) {
      bf16x8 bf_ = *(const bf16x8*)(&Bbf[(wv * 64 + jt * 16 + (l & 15)) * LDH + (l >> 4) * 8]);
#pragma unroll
      for (int rt = 0; rt < 4; ++rt)
        acc2[rt * 4 + jt] =
            __builtin_amdgcn_mfma_f32_16x16x32_bf16(af2[rt], bf_, acc2[rt * 4 + jt], 0, 0, 0);
    }
    __syncthreads();
  }
  // ---- epilogue: relu(h + TB) . Wo, reduce over j ----
  float part[16];
#pragma unroll
  for (int i = 0; i < 16; ++i) part[i] = 0.f;
#pragma unroll
  for (int jt = 0; jt < 4; ++jt) {
    int j = wv * 64 + jt * 16 + (l & 15);
    float woc = Wos[j];
#pragma unroll
    for (int rt = 0; rt < 4; ++rt)
#pragma unroll
      for (int r = 0; r < 4; ++r) {
        int t = t0 + rt * 16 + ((l >> 4) << 2) + r;
        float v = acc2[rt * 4 + jt][r] + TB[(size_t)t * HDIM + j];
        part[rt * 4 + r] = fmaf(fmaxf(v, 0.f), woc, part[rt * 4 + r]);
      }
  }
#pragma unroll
  for (int i = 0; i < 16; ++i) part[i] = dppadd<0x111, 0xf>(part[i]);
#pragma unroll
  for (int i = 0; i < 16; ++i) part[i] = dppadd<0x112, 0xf>(part[i]);
#pragma unroll
  for (int i = 0; i < 16; ++i) part[i] = dppadd<0x114, 0xf>(part[i]);
#pragma unroll
  for (int i = 0; i < 16; ++i) part[i] = dppadd<0x118, 0xf>(part[i]);
  if ((l & 15) == 15) {
#pragma unroll
    for (int rt = 0; rt < 4; ++rt)
#pragma unroll
      for (int r = 0; r < 4; ++r)
        predp[wv][rt * 16 + ((l >> 4) << 2) + r] = part[rt * 4 + r];
  }
  __syncthreads();
  if (tid < 64) {
    int t = t0 + tid;
    if (t < TDIM)
      out[(size_t)b * TDIM + t] =
          predp[0][tid] + predp[1][tid] + predp[2][tid] + predp[3][tid] + bo[0];
  }
}

// ---------------- launch ----------------
extern "C" void kernel_launch(void* const* d_in, const int* in_sizes, int n_in,
                              void* d_out, int out_size, void* d_ws, size_t ws_size,
                              hipStream_t stream) {
  const float* F     = (const float*)d_in[0];
  const float* text  = (const float*)d_in[1];
  const float* A     = (const float*)d_in[2];
  const float* gamma = (const float*)d_in[3];
  const float* beta  = (const float*)d_in[4];
  const float* Wh    = (const float*)d_in[5];
  const float* bh    = (const float*)d_in[6];
  const float* Wo    = (const float*)d_in[7];
  const float* bo    = (const float*)d_in[8];
  float* out = (float*)d_out;
  char* ws = (char*)d_ws;
  unsigned short* tAb  = (unsigned short*)(ws + OFS_TAB);
  float* TB     = (float*)(ws + OFS_TB);
  unsigned short* WhbT = (unsigned short*)(ws + OFS_WHT);
  ull* qpart    = (ull*)(ws + OFS_QPART);
  unsigned short* s1T  = (unsigned short*)(ws + OFS_S1T);
  unsigned short* FbT  = (unsigned short*)(ws + OFS_FBT);

  k_prep<<<512, 256, 0, stream>>>(F, Wh, text, A, bh, tAb, TB, WhbT, FbT, (uint4*)qpart);
  k_sinkhorn<<<dim3(BDIM, SBLK), 320, 0, stream>>>(F, tAb, gamma, beta, s1T, qpart);
  k_out<<<dim3(BDIM, 5), 256, 0, stream>>>(s1T, FbT, WhbT, TB, Wo, bo, out);
}